// Round 2
// baseline (30.633 us; speedup 1.0000x reference)
//
#include <hip/hip_runtime.h>
#include <math.h>

#define EPSF 1e-8f
#define INV_SQRT2F 0.70710678118654752f
#define INV_SQRT_2PIF 0.39894228040143268f

__device__ inline void max_gauss(float m1, float v1, float m2, float v2,
                                 float& mo, float& vo) {
    float alpha = sqrtf(v1 + v2 + EPSF);
    float beta  = (m1 - m2) / alpha;
    float e     = erff(beta * INV_SQRT2F);
    float cdf_b  = 0.5f * (1.0f + e);
    float cdf_nb = 0.5f * (1.0f - e);
    float pdf_b  = expf(-0.5f * beta * beta) * INV_SQRT_2PIF;
    mo = m1 * cdf_b + m2 * cdf_nb + alpha * pdf_b;
    vo = (v1 + m1 * m1) * cdf_b + (v2 + m2 * m2) * cdf_nb
       + (m1 + m2) * alpha * pdf_b - mo * mo + EPSF;
}

// x: (32, 2, 128, 64, 64) f32; out: (32, 2, 128, 32, 32) f32
// Block = (b, i): 1024 blocks x 512 threads (8 waves -> 32 waves/CU).
// thread: g = t>>5 in [0,16) plane-group, q = t&31 chunk index.
//   q encodes: r = q>>4 (row offset), qp = q&15 (column pair).
//   lane's float4 at plane p, row 2i+r, cols 4qp..4qp+3
//   -> contributes to output cols j0=2qp (s=0,1) and j1=2qp+1 (s=0,1).
// Plane p = it*16 + g; it<8 -> means (c = p), it>=8 -> vars (c = p-128).
__global__ __launch_bounds__(512) void dmp_kernel(const float* __restrict__ x,
                                                  float* __restrict__ out) {
    const size_t PL = 4096;  // 64*64 plane

    int blk = blockIdx.x;
    int b = blk >> 5;
    int i = blk & 31;
    int t = threadIdx.x;
    int q = t & 31;
    int g = t >> 5;      // 0..15
    int qp = q & 15;     // column-pair
    int r  = q >> 4;     // row offset 0/1

    const float* base = x + ((size_t)b * 256 + (size_t)g) * PL
                          + (size_t)(2 * i + r) * 64 + (size_t)(4 * qp);

    // am/av: (j0,s0),(j0,s1),(j1,s0),(j1,s1)
    float am[4] = {0.f, 0.f, 0.f, 0.f};
    float av[4] = {0.f, 0.f, 0.f, 0.f};

    #pragma unroll
    for (int it = 0; it < 16; ++it) {
        float4 d = *(const float4*)(base + (size_t)it * 16 * PL);
        if (it < 8) { am[0] += d.x; am[1] += d.y; am[2] += d.z; am[3] += d.w; }
        else        { av[0] += d.x; av[1] += d.y; av[2] += d.z; av[3] += d.w; }
    }

    __shared__ float red[16][32][9];  // [g][q][8 vals], pad 9
    #pragma unroll
    for (int k = 0; k < 4; ++k) {
        red[g][q][k]     = am[k];
        red[g][q][4 + k] = av[k];
    }
    __syncthreads();

    __shared__ float mv[2][32];
    if (t < 32) {
        int j  = t;
        int qh = j >> 1;
        int o  = (j & 1) * 2;  // 0 for j even (j0), 2 for j odd (j1)
        float sm[2][2] = {{0.f, 0.f}, {0.f, 0.f}};  // [r][s]
        float sv[2][2] = {{0.f, 0.f}, {0.f, 0.f}};
        #pragma unroll
        for (int gg = 0; gg < 16; ++gg) {
            #pragma unroll
            for (int rr = 0; rr < 2; ++rr) {
                int qq = rr * 16 + qh;
                sm[rr][0] += red[gg][qq][o];
                sm[rr][1] += red[gg][qq][o + 1];
                sv[rr][0] += red[gg][qq][4 + o];
                sv[rr][1] += red[gg][qq][4 + o + 1];
            }
        }
        float hm1, hv1, hm2, hv2, m, v;
        max_gauss(sm[0][0], sv[0][0], sm[0][1], sv[0][1], hm1, hv1);
        max_gauss(sm[1][0], sv[1][0], sm[1][1], sv[1][1], hm2, hv2);
        max_gauss(hm1, hv1, hm2, hv2, m, v);
        mv[0][j] = m;
        mv[1][j] = v;
    }
    __syncthreads();

    // Output broadcast: out[((b*2+u)*128 + c)*1024 + i*32 + ...]
    // 8192 floats = 2048 float4 per block; 4 iterations of 512 threads.
    #pragma unroll
    for (int w = 0; w < 4; ++w) {
        int idx = w * 512 + t;   // 0..2047
        int u   = idx >> 10;
        int rem = idx & 1023;
        int c   = rem >> 3;
        int jq  = rem & 7;
        float4 val;
        val.x = mv[u][jq * 4 + 0];
        val.y = mv[u][jq * 4 + 1];
        val.z = mv[u][jq * 4 + 2];
        val.w = mv[u][jq * 4 + 3];
        size_t off = (((size_t)b * 2 + u) * 128 + (size_t)c) * 1024
                   + (size_t)i * 32 + (size_t)(jq * 4);
        *(float4*)(out + off) = val;
    }
}

extern "C" void kernel_launch(void* const* d_in, const int* in_sizes, int n_in,
                              void* d_out, int out_size, void* d_ws, size_t ws_size,
                              hipStream_t stream) {
    const float* x = (const float*)d_in[0];
    float* out = (float*)d_out;
    dim3 grid(1024), block(512);
    hipLaunchKernelGGL(dmp_kernel, grid, block, 0, stream, x, out);
}